// Round 7
// baseline (145.903 us; speedup 1.0000x reference)
//
#include <hip/hip_runtime.h>

// Involution2d: B=8, C=256, G=4 (Cpg=64), H=W=Ho=Wo=64, K=7, PAD=3, STRIDE=1.
// out[b, g*64+c, y, x] = sum_{kh,kw} in[b, g*64+c, y+kh-3, x+kw-3] * w[b,g,kh,kw,y,x] + bias[g*64+c]
//
// Round-7 = round-6 + forced weight residency. r6 readout: VGPR_Count=64
// (allocator squeezed for 8 waves/SIMD; wA/wB=56 regs can't stay live ->
// weight loads sank to their uses -> exposed L2 latency, VALUBusy 23%).
//  - amdgpu_waves_per_eu(4,4): occupancy target fixed at 4 waves/SIMD,
//    budget 128; demand ~105 -> no squeeze incentive, no spill (r5's lesson:
//    demand must sit well under 128 -- it does).
//  - PINW(buf) opaque asm between the previous STEP and the consuming STEP:
//    loads must complete by the pin (one full STEP of latency cover) and
//    cannot be sunk/remat'd past it.
// Bank conflicts: r6's residual 8.8M ~= 688K b128 reads x intrinsic 8-phase
// baseline (wave64 x 16B = 1024B @128B/cyc); swizzle already removed the
// real conflicts (12.55M -> 8.83M). Not chased further.

#define BLK_X 16
#define BLK_Y 16
#define NTHR  256
#define NC    4
#define ROWS  16                  // output rows per block (= BLK_Y)
#define S_ROWS 22                 // ROWS + 6 halo
#define ST_F4 24                  // float4 stride per staged row (mult of 8)
#define S_CH_F4 (S_ROWS * ST_F4)  // 528 float4 per channel
#define SEGS (S_ROWS * 18)        // 396 valid float4 per channel

// load 7 weight float4 for kernel row KH into buf (coalesced dwordx4)
#define LOADW(buf, KH) do {                                                 \
    _Pragma("unroll")                                                       \
    for (int kw_ = 0; kw_ < 7; ++kw_)                                       \
        buf[kw_] = *(const float4*)(wb + (size_t)((KH) * 7 + kw_) * 4096);  \
} while (0)

// opaque pin: forces buf's 28 floats live & completed here; placed right
// before the STEP that consumes buf (one STEP after its LOADW).
#define PINW(buf) do {                                                      \
    asm volatile("" : "+v"(buf[0].x), "+v"(buf[0].y), "+v"(buf[0].z),       \
                      "+v"(buf[0].w), "+v"(buf[1].x), "+v"(buf[1].y),       \
                      "+v"(buf[1].z), "+v"(buf[1].w), "+v"(buf[2].x),       \
                      "+v"(buf[2].y), "+v"(buf[2].z), "+v"(buf[2].w),       \
                      "+v"(buf[3].x), "+v"(buf[3].y), "+v"(buf[3].z),       \
                      "+v"(buf[3].w), "+v"(buf[4].x), "+v"(buf[4].y),       \
                      "+v"(buf[4].z), "+v"(buf[4].w), "+v"(buf[5].x),       \
                      "+v"(buf[5].y), "+v"(buf[5].z), "+v"(buf[5].w),       \
                      "+v"(buf[6].x), "+v"(buf[6].y), "+v"(buf[6].z),       \
                      "+v"(buf[6].w));                                      \
} while (0)

// one kh step: 4 channels x (3 swizzled b128 reads + 28 FMAs) with weights W
#define STEP(KH, W) do {                                                    \
    const int row_ = ty + (KH);          /* staged row 0..21 */             \
    const int xm_  = row_ & 7;                                              \
    _Pragma("unroll")                                                       \
    for (int ch_ = 0; ch_ < NC; ++ch_) {                                    \
        const float4* lp_ = lds4 + ch_ * S_CH_F4 + row_ * ST_F4;            \
        float4 v0_ = lp_[(tx + 0) ^ xm_];                                   \
        float4 v1_ = lp_[(tx + 1) ^ xm_];                                   \
        float4 v2_ = lp_[(tx + 2) ^ xm_];                                   \
        float vals_[12] = {v0_.x, v0_.y, v0_.z, v0_.w,                      \
                           v1_.x, v1_.y, v1_.z, v1_.w,                      \
                           v2_.x, v2_.y, v2_.z, v2_.w};                     \
        _Pragma("unroll")                                                   \
        for (int kw_ = 0; kw_ < 7; ++kw_) {                                 \
            acc[ch_][0] += vals_[kw_ + 1] * W[kw_].x;                       \
            acc[ch_][1] += vals_[kw_ + 2] * W[kw_].y;                       \
            acc[ch_][2] += vals_[kw_ + 3] * W[kw_].z;                       \
            acc[ch_][3] += vals_[kw_ + 4] * W[kw_].w;                       \
        }                                                                   \
    }                                                                       \
} while (0)

__global__ __launch_bounds__(NTHR, 4)
__attribute__((amdgpu_waves_per_eu(4, 4)))
void involution_kernel(const float* __restrict__ in,
                       const float* __restrict__ w,
                       const float* __restrict__ bias,
                       float* __restrict__ out) {
    __shared__ float4 lds4[NC * S_CH_F4];   // 33,792 B -> 4 blocks/CU by LDS

    const int tx  = threadIdx.x;            // 0..15 (x-quad)
    const int ty  = threadIdx.y;            // 0..15 (row)
    const int tid = ty * BLK_X + tx;
    const int x0  = tx * 4;
    const int Y0  = blockIdx.x * ROWS;
    const int y   = Y0 + ty;
    const int c0  = blockIdx.y * NC;
    const int bz  = blockIdx.z;             // b*4 + g
    const int g   = bz & 3;

    const float* inb  = in  + (size_t)bz * 64 * 4096;
    float*       outb = out + (size_t)bz * 64 * 4096;
    const float* wb   = w   + (size_t)bz * 49 * 4096 + y * 64 + x0;

    float4 wA[7], wB[7];
    LOADW(wA, 0);                 // kh=0 weights hide under staging

    // ---- stage NC channels once, swizzled, single barrier ----
    // cols t=0..17; halo t=0/17 stays zero; data t=1..16 maps to gx=4(t-1);
    // slot = row*24 + (t ^ (row&7)).
    #pragma unroll
    for (int ch = 0; ch < NC; ++ch) {
        const float* p = inb + (size_t)(c0 + ch) * 4096;
        #pragma unroll
        for (int j = 0; j < 2; ++j) {
            int e = tid + j * NTHR;          // 0..511, guard < 396
            if (e < SEGS) {
                int row = e / 18;
                int t   = e - row * 18;
                int gy  = Y0 + row - 3;
                float4 v = make_float4(0.f, 0.f, 0.f, 0.f);
                if (t >= 1 && t <= 16 && gy >= 0 && gy < 64)
                    v = *(const float4*)(p + gy * 64 + (t - 1) * 4);
                lds4[ch * S_CH_F4 + row * ST_F4 + (t ^ (row & 7))] = v;
            }
        }
    }

    float bvs[NC];
    #pragma unroll
    for (int c = 0; c < NC; ++c) bvs[c] = bias[g * 64 + c0 + c];

    LOADW(wB, 1);                 // kh=1 weights hide under the barrier
    __syncthreads();

    float acc[NC][4];
    #pragma unroll
    for (int c = 0; c < NC; ++c) {
        acc[c][0] = 0.f; acc[c][1] = 0.f; acc[c][2] = 0.f; acc[c][3] = 0.f;
    }

    // ---- depth-2 pipelined kh ladder; PINW(X) right before STEP(·, X)
    //      forces X's loads to have issued >= one STEP earlier.
    PINW(wA);
    STEP(0, wA);  LOADW(wA, 2);
    PINW(wB);
    STEP(1, wB);  LOADW(wB, 3);
    PINW(wA);
    STEP(2, wA);  LOADW(wA, 4);
    PINW(wB);
    STEP(3, wB);  LOADW(wB, 5);
    PINW(wA);
    STEP(4, wA);  LOADW(wA, 6);
    PINW(wB);
    STEP(5, wB);
    PINW(wA);
    STEP(6, wA);

    // ---- epilogue ----
    #pragma unroll
    for (int c = 0; c < NC; ++c) {
        float4 o;
        o.x = acc[c][0] + bvs[c];
        o.y = acc[c][1] + bvs[c];
        o.z = acc[c][2] + bvs[c];
        o.w = acc[c][3] + bvs[c];
        *(float4*)(outb + (size_t)(c0 + c) * 4096 + y * 64 + x0) = o;
    }
}

extern "C" void kernel_launch(void* const* d_in, const int* in_sizes, int n_in,
                              void* d_out, int out_size, void* d_ws, size_t ws_size,
                              hipStream_t stream) {
    const float* in   = (const float*)d_in[0];  // (8,256,64,64)
    const float* wgt  = (const float*)d_in[1];  // (8,4,7,7,64,64)
    const float* bias = (const float*)d_in[2];  // (256,)
    float* out = (float*)d_out;                 // (8,256,64,64)

    dim3 block(BLK_X, BLK_Y, 1);                 // 256 threads = 4 waves
    dim3 grid(64 / ROWS, 64 / NC, 32);           // (4, 16, 32) = 2048 blocks
    involution_kernel<<<grid, block, 0, stream>>>(in, wgt, bias, out);
}

// Round 8
// 123.762 us; speedup vs baseline: 1.1789x; 1.1789x over previous
//
#include <hip/hip_runtime.h>

// Involution2d: B=8, C=256, G=4 (Cpg=64), H=W=Ho=Wo=64, K=7, PAD=3, STRIDE=1.
// out[b, g*64+c, y, x] = sum_{kh,kw} in[b, g*64+c, y+kh-3, x+kw-3] * w[b,g,kh,kw,y,x] + bias[g*64+c]
//
// Round-8. Empirical allocator law from r0-r7 (by block size, not attribute):
//   256-thr blocks -> grant stuck at 40-64 VGPR (r1/r2/r6/r7, every attr
//   tried incl waves_per_eu(4,4)+pins -> r7 SPILLED at 64 rather than grant);
//   128-thr + launch_bounds(128,2) -> grant 128 (r0).
// So: 128-thr blocks, demand ~99 <= grant 128. The depth-2 weight pipeline
// (wA/wB 56 regs) + acc 16 + vals 12 + addr ~15 fits for the first time ->
// loads stay hoisted, pins are satisfiable without spill.
//  - Geometry: r6's swizzled stage-once LDS, ROWS=8 -> LDS 21,504B ->
//    7 blocks/CU (14 waves, 44% cap vs r6's 33% realized).
//  - Decisive readouts: VGPR ~120-128 (not 64), WRITE_SIZE ~33MB (no spill).

#define BLK_X 16
#define BLK_Y 8
#define NTHR  128
#define NC    4
#define ROWS  8                   // output rows per block (= BLK_Y)
#define S_ROWS 14                 // ROWS + 6 halo
#define ST_F4 24                  // float4 stride per staged row (mult of 8)
#define S_CH_F4 (S_ROWS * ST_F4)  // 336 float4 per channel
#define SEGS (S_ROWS * 18)        // 252 valid float4 per channel

// load 7 weight float4 for kernel row KH into buf (coalesced dwordx4)
#define LOADW(buf, KH) do {                                                 \
    _Pragma("unroll")                                                       \
    for (int kw_ = 0; kw_ < 7; ++kw_)                                       \
        buf[kw_] = *(const float4*)(wb + (size_t)((KH) * 7 + kw_) * 4096);  \
} while (0)

// opaque pin: forces buf's 28 floats live & loads complete here; placed
// right before the STEP that consumes buf (one STEP after its LOADW).
#define PINW(buf) do {                                                      \
    asm volatile("" : "+v"(buf[0].x), "+v"(buf[0].y), "+v"(buf[0].z),       \
                      "+v"(buf[0].w), "+v"(buf[1].x), "+v"(buf[1].y),       \
                      "+v"(buf[1].z), "+v"(buf[1].w), "+v"(buf[2].x),       \
                      "+v"(buf[2].y), "+v"(buf[2].z), "+v"(buf[2].w),       \
                      "+v"(buf[3].x), "+v"(buf[3].y), "+v"(buf[3].z),       \
                      "+v"(buf[3].w), "+v"(buf[4].x), "+v"(buf[4].y),       \
                      "+v"(buf[4].z), "+v"(buf[4].w), "+v"(buf[5].x),       \
                      "+v"(buf[5].y), "+v"(buf[5].z), "+v"(buf[5].w),       \
                      "+v"(buf[6].x), "+v"(buf[6].y), "+v"(buf[6].z),       \
                      "+v"(buf[6].w));                                      \
} while (0)

// one kh step: 4 channels x (3 swizzled b128 reads + 28 FMAs) with weights W
#define STEP(KH, W) do {                                                    \
    const int row_ = ty + (KH);          /* staged row 0..13 */             \
    const int xm_  = row_ & 7;                                              \
    _Pragma("unroll")                                                       \
    for (int ch_ = 0; ch_ < NC; ++ch_) {                                    \
        const float4* lp_ = lds4 + ch_ * S_CH_F4 + row_ * ST_F4;            \
        float4 v0_ = lp_[(tx + 0) ^ xm_];                                   \
        float4 v1_ = lp_[(tx + 1) ^ xm_];                                   \
        float4 v2_ = lp_[(tx + 2) ^ xm_];                                   \
        float vals_[12] = {v0_.x, v0_.y, v0_.z, v0_.w,                      \
                           v1_.x, v1_.y, v1_.z, v1_.w,                      \
                           v2_.x, v2_.y, v2_.z, v2_.w};                     \
        _Pragma("unroll")                                                   \
        for (int kw_ = 0; kw_ < 7; ++kw_) {                                 \
            acc[ch_][0] += vals_[kw_ + 1] * W[kw_].x;                       \
            acc[ch_][1] += vals_[kw_ + 2] * W[kw_].y;                       \
            acc[ch_][2] += vals_[kw_ + 3] * W[kw_].z;                       \
            acc[ch_][3] += vals_[kw_ + 4] * W[kw_].w;                       \
        }                                                                   \
    }                                                                       \
} while (0)

__global__ __launch_bounds__(NTHR, 2)
void involution_kernel(const float* __restrict__ in,
                       const float* __restrict__ w,
                       const float* __restrict__ bias,
                       float* __restrict__ out) {
    __shared__ float4 lds4[NC * S_CH_F4];   // 21,504 B -> 7 blocks/CU by LDS

    const int tx  = threadIdx.x;            // 0..15 (x-quad)
    const int ty  = threadIdx.y;            // 0..7  (row)
    const int tid = ty * BLK_X + tx;        // 0..127
    const int x0  = tx * 4;
    const int Y0  = blockIdx.x * ROWS;
    const int y   = Y0 + ty;
    const int c0  = blockIdx.y * NC;
    const int bz  = blockIdx.z;             // b*4 + g
    const int g   = bz & 3;

    const float* inb  = in  + (size_t)bz * 64 * 4096;
    float*       outb = out + (size_t)bz * 64 * 4096;
    const float* wb   = w   + (size_t)bz * 49 * 4096 + y * 64 + x0;

    float4 wA[7], wB[7];
    LOADW(wA, 0);                 // kh=0 weights hide under staging

    // ---- stage NC channels once, swizzled, single barrier ----
    // cols t=0..17; halo t=0/17 stays zero; data t=1..16 maps to gx=4(t-1);
    // slot = row*24 + (t ^ (row&7)).
    #pragma unroll
    for (int ch = 0; ch < NC; ++ch) {
        const float* p = inb + (size_t)(c0 + ch) * 4096;
        #pragma unroll
        for (int j = 0; j < 2; ++j) {
            int e = tid + j * NTHR;          // 0..255, guard < 252
            if (e < SEGS) {
                int row = e / 18;
                int t   = e - row * 18;
                int gy  = Y0 + row - 3;
                float4 v = make_float4(0.f, 0.f, 0.f, 0.f);
                if (t >= 1 && t <= 16 && gy >= 0 && gy < 64)
                    v = *(const float4*)(p + gy * 64 + (t - 1) * 4);
                lds4[ch * S_CH_F4 + row * ST_F4 + (t ^ (row & 7))] = v;
            }
        }
    }

    float bvs[NC];
    #pragma unroll
    for (int c = 0; c < NC; ++c) bvs[c] = bias[g * 64 + c0 + c];

    LOADW(wB, 1);                 // kh=1 weights hide under the barrier
    __syncthreads();

    float acc[NC][4];
    #pragma unroll
    for (int c = 0; c < NC; ++c) {
        acc[c][0] = 0.f; acc[c][1] = 0.f; acc[c][2] = 0.f; acc[c][3] = 0.f;
    }

    // ---- depth-2 pipelined kh ladder; PINW(X) right before STEP(·, X)
    //      forces X's loads to be in flight >= one full STEP earlier.
    PINW(wA);
    STEP(0, wA);  LOADW(wA, 2);
    PINW(wB);
    STEP(1, wB);  LOADW(wB, 3);
    PINW(wA);
    STEP(2, wA);  LOADW(wA, 4);
    PINW(wB);
    STEP(3, wB);  LOADW(wB, 5);
    PINW(wA);
    STEP(4, wA);  LOADW(wA, 6);
    PINW(wB);
    STEP(5, wB);
    PINW(wA);
    STEP(6, wA);

    // ---- epilogue ----
    #pragma unroll
    for (int c = 0; c < NC; ++c) {
        float4 o;
        o.x = acc[c][0] + bvs[c];
        o.y = acc[c][1] + bvs[c];
        o.z = acc[c][2] + bvs[c];
        o.w = acc[c][3] + bvs[c];
        *(float4*)(outb + (size_t)(c0 + c) * 4096 + y * 64 + x0) = o;
    }
}

extern "C" void kernel_launch(void* const* d_in, const int* in_sizes, int n_in,
                              void* d_out, int out_size, void* d_ws, size_t ws_size,
                              hipStream_t stream) {
    const float* in   = (const float*)d_in[0];  // (8,256,64,64)
    const float* wgt  = (const float*)d_in[1];  // (8,4,7,7,64,64)
    const float* bias = (const float*)d_in[2];  // (256,)
    float* out = (float*)d_out;                 // (8,256,64,64)

    dim3 block(BLK_X, BLK_Y, 1);                 // 128 threads = 2 waves
    dim3 grid(64 / ROWS, 64 / NC, 32);           // (8, 16, 32) = 4096 blocks
    involution_kernel<<<grid, block, 0, stream>>>(in, wgt, bias, out);
}